// Round 1
// baseline (1778.898 us; speedup 1.0000x reference)
//
#include <hip/hip_runtime.h>
#include <cstddef>

#define B_DIM 4
#define T_DIM 2048
#define C_DIM 1024
#define H_DIM 16
#define D_DIM 64
#define C3_DIM 3072

// ---------------------------------------------------------------------------
// Generic fp32 GEMM with bias: Cmat[M,N] = A[M,K] @ B[K,N] + bias[N]
// 128x128 block tile, BK=16, 256 threads, 8x8 register tile per thread.
// As stored k-major (transposed) so compute reads are conflict-free float4.
// ---------------------------------------------------------------------------
__global__ __launch_bounds__(256) void sgemm_bias(
    const float* __restrict__ A, const float* __restrict__ B,
    const float* __restrict__ bias, float* __restrict__ Cmat,
    int M, int N, int K)
{
    __shared__ float As[16][128];
    __shared__ float Bs[16][128];
    const int tid = threadIdx.x;
    const int tx = tid & 15;   // n-tile group
    const int ty = tid >> 4;   // m-tile group
    const int m0 = blockIdx.y * 128;
    const int n0 = blockIdx.x * 128;

    float acc[8][8];
#pragma unroll
    for (int i = 0; i < 8; ++i)
#pragma unroll
        for (int j = 0; j < 8; ++j) acc[i][j] = 0.f;

    for (int k0 = 0; k0 < K; k0 += 16) {
#pragma unroll
        for (int t = 0; t < 2; ++t) {
            int idx = tid + t * 256;
            // A tile: 128 rows x 16 k  (store transposed into As[k][m])
            int ar = idx >> 2, ak = (idx & 3) * 4;
            float4 av = *(const float4*)&A[(size_t)(m0 + ar) * K + k0 + ak];
            As[ak + 0][ar] = av.x;
            As[ak + 1][ar] = av.y;
            As[ak + 2][ar] = av.z;
            As[ak + 3][ar] = av.w;
            // B tile: 16 rows x 128 n
            int br = idx >> 5, bc = (idx & 31) * 4;
            *(float4*)&Bs[br][bc] =
                *(const float4*)&B[(size_t)(k0 + br) * N + n0 + bc];
        }
        __syncthreads();
#pragma unroll
        for (int kk = 0; kk < 16; ++kk) {
            float a[8], bv[8];
            *(float4*)&a[0] = *(const float4*)&As[kk][ty * 8];
            *(float4*)&a[4] = *(const float4*)&As[kk][ty * 8 + 4];
            *(float4*)&bv[0] = *(const float4*)&Bs[kk][tx * 8];
            *(float4*)&bv[4] = *(const float4*)&Bs[kk][tx * 8 + 4];
#pragma unroll
            for (int i = 0; i < 8; ++i)
#pragma unroll
                for (int j = 0; j < 8; ++j)
                    acc[i][j] = fmaf(a[i], bv[j], acc[i][j]);
        }
        __syncthreads();
    }

#pragma unroll
    for (int i = 0; i < 8; ++i) {
        size_t row = (size_t)(m0 + ty * 8 + i);
#pragma unroll
        for (int j4 = 0; j4 < 8; j4 += 4) {
            int col = n0 + tx * 8 + j4;
            float4 o;
            o.x = acc[i][j4 + 0] + bias[col + 0];
            o.y = acc[i][j4 + 1] + bias[col + 1];
            o.z = acc[i][j4 + 2] + bias[col + 2];
            o.w = acc[i][j4 + 3] + bias[col + 3];
            *(float4*)&Cmat[row * N + col] = o;
        }
    }
}

// ---------------------------------------------------------------------------
// RoPE in place on q and k slices of qkv (B,T,3C). One thread per pair index
// (b,t,h,i) with i < D/2; rotates both the q and the k pair.
// ---------------------------------------------------------------------------
__global__ __launch_bounds__(256) void rope_kernel(float* __restrict__ qkv)
{
    int idx = blockIdx.x * 256 + threadIdx.x;   // B*T*H*32 threads
    int i = idx & 31;
    int h = (idx >> 5) & 15;
    int t = (idx >> 9) & (T_DIM - 1);
    int b = idx >> 20;

    float theta = powf(10000.0f, -2.0f * (float)i / 64.0f);
    float ang = (float)t * theta;
    float s, c;
    sincosf(ang, &s, &c);

    size_t base = ((size_t)(b * T_DIM + t)) * C3_DIM + h * D_DIM + 2 * i;
    // q
    float2 q2 = *(float2*)&qkv[base];
    float2 qo;
    qo.x = q2.x * c - q2.y * s;
    qo.y = q2.x * s + q2.y * c;
    *(float2*)&qkv[base] = qo;
    // k (offset C within the 3C dim)
    float2 k2 = *(float2*)&qkv[base + C_DIM];
    float2 ko;
    ko.x = k2.x * c - k2.y * s;
    ko.y = k2.x * s + k2.y * c;
    *(float2*)&qkv[base + C_DIM] = ko;
}

// ---------------------------------------------------------------------------
// Flash-style causal attention, fp32.
// Block = (qtile, b*H+h), 256 threads as 16(tx: k/d cols) x 16(ty: q rows /4).
// Q,K stored d-major (transposed) in LDS -> conflict-free float4 S-compute.
// P overlays K's buffer after a barrier. Online softmax with 16-lane shfl.
// ---------------------------------------------------------------------------
__global__ __launch_bounds__(256) void attn_kernel(
    const float* __restrict__ qkv, float* __restrict__ y)
{
    __shared__ float QsT[64][68];  // [d][row]
    __shared__ float SP[64][68];   // phase 1: K^T [d][col]; phase 2: P [row][col]
    __shared__ float Vs[64][68];   // [col][d]

    const int qt = blockIdx.x;            // 0..31
    const int bh = blockIdx.y;            // 0..63
    const int b = bh >> 4, h = bh & 15;
    const int tid = threadIdx.x;
    const int tx = tid & 15;              // col group (k / d), 4 wide
    const int ty = tid >> 4;              // row group (q), 4 wide

    const float* qbase = qkv + (size_t)b * T_DIM * C3_DIM + h * D_DIM;
    const float* kbase = qbase + C_DIM;
    const float* vbase = qbase + 2 * C_DIM;

    // Load Q tile (transposed, pre-scaled by 1/sqrt(D))
#pragma unroll
    for (int it = 0; it < 4; ++it) {
        int row = (tid >> 4) + it * 16;
        int d4 = (tid & 15) * 4;
        float4 v4 = *(const float4*)&qbase[(size_t)(qt * 64 + row) * C3_DIM + d4];
        QsT[d4 + 0][row] = v4.x * 0.125f;
        QsT[d4 + 1][row] = v4.y * 0.125f;
        QsT[d4 + 2][row] = v4.z * 0.125f;
        QsT[d4 + 3][row] = v4.w * 0.125f;
    }

    float m_i[4], l_i[4], acc[4][4];
#pragma unroll
    for (int i = 0; i < 4; ++i) {
        m_i[i] = -1e30f;
        l_i[i] = 0.f;
#pragma unroll
        for (int j = 0; j < 4; ++j) acc[i][j] = 0.f;
    }

    for (int kt = 0; kt <= qt; ++kt) {
        __syncthreads();  // protect SP/Vs overwrite vs previous PV reads
#pragma unroll
        for (int it = 0; it < 4; ++it) {
            int row = (tid >> 4) + it * 16;
            int d4 = (tid & 15) * 4;
            float4 kv4 = *(const float4*)&kbase[(size_t)(kt * 64 + row) * C3_DIM + d4];
            SP[d4 + 0][row] = kv4.x;
            SP[d4 + 1][row] = kv4.y;
            SP[d4 + 2][row] = kv4.z;
            SP[d4 + 3][row] = kv4.w;
            *(float4*)&Vs[row][d4] =
                *(const float4*)&vbase[(size_t)(kt * 64 + row) * C3_DIM + d4];
        }
        __syncthreads();

        // S = (Q/sqrt(D)) @ K^T  (4x4 per thread)
        float s[4][4];
#pragma unroll
        for (int i = 0; i < 4; ++i)
#pragma unroll
            for (int j = 0; j < 4; ++j) s[i][j] = 0.f;

#pragma unroll 4
        for (int d = 0; d < 64; ++d) {
            float4 qf = *(const float4*)&QsT[d][ty * 4];
            float4 kf = *(const float4*)&SP[d][tx * 4];
            s[0][0] = fmaf(qf.x, kf.x, s[0][0]);
            s[0][1] = fmaf(qf.x, kf.y, s[0][1]);
            s[0][2] = fmaf(qf.x, kf.z, s[0][2]);
            s[0][3] = fmaf(qf.x, kf.w, s[0][3]);
            s[1][0] = fmaf(qf.y, kf.x, s[1][0]);
            s[1][1] = fmaf(qf.y, kf.y, s[1][1]);
            s[1][2] = fmaf(qf.y, kf.z, s[1][2]);
            s[1][3] = fmaf(qf.y, kf.w, s[1][3]);
            s[2][0] = fmaf(qf.z, kf.x, s[2][0]);
            s[2][1] = fmaf(qf.z, kf.y, s[2][1]);
            s[2][2] = fmaf(qf.z, kf.z, s[2][2]);
            s[2][3] = fmaf(qf.z, kf.w, s[2][3]);
            s[3][0] = fmaf(qf.w, kf.x, s[3][0]);
            s[3][1] = fmaf(qf.w, kf.y, s[3][1]);
            s[3][2] = fmaf(qf.w, kf.z, s[3][2]);
            s[3][3] = fmaf(qf.w, kf.w, s[3][3]);
        }

        // causal mask (only the diagonal tile is partial)
        if (kt == qt) {
#pragma unroll
            for (int i = 0; i < 4; ++i)
#pragma unroll
                for (int j = 0; j < 4; ++j)
                    if (tx * 4 + j > ty * 4 + i) s[i][j] = -1e30f;
        }

        // online softmax update (rows owned per-thread, reduced across 16 tx lanes)
        float p[4][4];
#pragma unroll
        for (int i = 0; i < 4; ++i) {
            float mt = fmaxf(fmaxf(s[i][0], s[i][1]), fmaxf(s[i][2], s[i][3]));
#pragma unroll
            for (int off = 1; off < 16; off <<= 1)
                mt = fmaxf(mt, __shfl_xor(mt, off));
            float mnew = fmaxf(m_i[i], mt);
            float alpha = __expf(m_i[i] - mnew);
            float lloc = 0.f;
#pragma unroll
            for (int j = 0; j < 4; ++j) {
                p[i][j] = __expf(s[i][j] - mnew);
                lloc += p[i][j];
            }
#pragma unroll
            for (int off = 1; off < 16; off <<= 1)
                lloc += __shfl_xor(lloc, off);
            l_i[i] = l_i[i] * alpha + lloc;
            m_i[i] = mnew;
#pragma unroll
            for (int j = 0; j < 4; ++j) acc[i][j] *= alpha;
        }

        __syncthreads();  // everyone done reading K^T from SP
#pragma unroll
        for (int i = 0; i < 4; ++i) {
            float4 pv = make_float4(p[i][0], p[i][1], p[i][2], p[i][3]);
            *(float4*)&SP[ty * 4 + i][tx * 4] = pv;
        }
        __syncthreads();

        // O += P @ V  (thread owns rows ty*4.., d cols tx*4..)
#pragma unroll 4
        for (int c = 0; c < 64; ++c) {
            float4 vv = *(const float4*)&Vs[c][tx * 4];
            float pr0 = SP[ty * 4 + 0][c];
            float pr1 = SP[ty * 4 + 1][c];
            float pr2 = SP[ty * 4 + 2][c];
            float pr3 = SP[ty * 4 + 3][c];
            acc[0][0] = fmaf(pr0, vv.x, acc[0][0]);
            acc[0][1] = fmaf(pr0, vv.y, acc[0][1]);
            acc[0][2] = fmaf(pr0, vv.z, acc[0][2]);
            acc[0][3] = fmaf(pr0, vv.w, acc[0][3]);
            acc[1][0] = fmaf(pr1, vv.x, acc[1][0]);
            acc[1][1] = fmaf(pr1, vv.y, acc[1][1]);
            acc[1][2] = fmaf(pr1, vv.z, acc[1][2]);
            acc[1][3] = fmaf(pr1, vv.w, acc[1][3]);
            acc[2][0] = fmaf(pr2, vv.x, acc[2][0]);
            acc[2][1] = fmaf(pr2, vv.y, acc[2][1]);
            acc[2][2] = fmaf(pr2, vv.z, acc[2][2]);
            acc[2][3] = fmaf(pr2, vv.w, acc[2][3]);
            acc[3][0] = fmaf(pr3, vv.x, acc[3][0]);
            acc[3][1] = fmaf(pr3, vv.y, acc[3][1]);
            acc[3][2] = fmaf(pr3, vv.z, acc[3][2]);
            acc[3][3] = fmaf(pr3, vv.w, acc[3][3]);
        }
    }

    // epilogue: normalize and write y (B,T,C) with heads re-interleaved
#pragma unroll
    for (int i = 0; i < 4; ++i) {
        float invl = 1.0f / l_i[i];
        float4 o = make_float4(acc[i][0] * invl, acc[i][1] * invl,
                               acc[i][2] * invl, acc[i][3] * invl);
        size_t row = (size_t)b * T_DIM + qt * 64 + ty * 4 + i;
        *(float4*)&y[row * C_DIM + h * D_DIM + tx * 4] = o;
    }
}

// ---------------------------------------------------------------------------
extern "C" void kernel_launch(void* const* d_in, const int* in_sizes, int n_in,
                              void* d_out, int out_size, void* d_ws, size_t ws_size,
                              hipStream_t stream)
{
    const float* x     = (const float*)d_in[0];
    const float* Wqkv  = (const float*)d_in[1];
    const float* bqkv  = (const float*)d_in[2];
    const float* Wproj = (const float*)d_in[3];
    const float* bproj = (const float*)d_in[4];
    float* out = (float*)d_out;

    float* qkv = (float*)d_ws;                              // B*T*3C fp32 (96 MB)
    float* y   = qkv + (size_t)B_DIM * T_DIM * C3_DIM;      // B*T*C fp32 (32 MB)

    dim3 blk(256);

    // qkv = x @ W_qkv + b_qkv
    sgemm_bias<<<dim3(C3_DIM / 128, (B_DIM * T_DIM) / 128), blk, 0, stream>>>(
        x, Wqkv, bqkv, qkv, B_DIM * T_DIM, C3_DIM, C_DIM);

    // RoPE on q,k in place
    rope_kernel<<<dim3((B_DIM * T_DIM * H_DIM * (D_DIM / 2)) / 256), blk, 0,
                  stream>>>(qkv);

    // flash attention -> y (B,T,C)
    attn_kernel<<<dim3(T_DIM / 64, B_DIM * H_DIM), blk, 0, stream>>>(qkv, y);

    // out = y @ W_proj + b_proj
    sgemm_bias<<<dim3(C_DIM / 128, (B_DIM * T_DIM) / 128), blk, 0, stream>>>(
        y, Wproj, bproj, out, B_DIM * T_DIM, C_DIM, C_DIM);
}

// Round 2
// 1081.847 us; speedup vs baseline: 1.6443x; 1.6443x over previous
//
#include <hip/hip_runtime.h>
#include <cstddef>

#define B_DIM 4
#define T_DIM 2048
#define C_DIM 1024
#define H_DIM 16
#define D_DIM 64
#define C3_DIM 3072

typedef __attribute__((ext_vector_type(8))) __bf16 bf16x8;
typedef __attribute__((ext_vector_type(4))) __bf16 bf16x4;
typedef __attribute__((ext_vector_type(4))) float f32x4;

typedef const __attribute__((address_space(1))) unsigned int* gptr_t;
typedef __attribute__((address_space(3))) unsigned int* lptr_t;

// ---------------------------------------------------------------------------
// fp32 GEMM with bias: Cmat[M,N] = A[M,K] @ B[K,N] + bias[N], A row stride lda.
// 128x128 tile, BK=16, 256 threads, 8x8 register tile. (unchanged from R1,
// plus lda so proj can read y out of the qkv k-slice)
// ---------------------------------------------------------------------------
__global__ __launch_bounds__(256) void sgemm_bias(
    const float* __restrict__ A, const float* __restrict__ B,
    const float* __restrict__ bias, float* __restrict__ Cmat,
    int M, int N, int K, int lda)
{
    __shared__ float As[16][128];
    __shared__ float Bs[16][128];
    const int tid = threadIdx.x;
    const int tx = tid & 15;
    const int ty = tid >> 4;
    const int m0 = blockIdx.y * 128;
    const int n0 = blockIdx.x * 128;

    float acc[8][8];
#pragma unroll
    for (int i = 0; i < 8; ++i)
#pragma unroll
        for (int j = 0; j < 8; ++j) acc[i][j] = 0.f;

    for (int k0 = 0; k0 < K; k0 += 16) {
#pragma unroll
        for (int t = 0; t < 2; ++t) {
            int idx = tid + t * 256;
            int ar = idx >> 2, ak = (idx & 3) * 4;
            float4 av = *(const float4*)&A[(size_t)(m0 + ar) * lda + k0 + ak];
            As[ak + 0][ar] = av.x;
            As[ak + 1][ar] = av.y;
            As[ak + 2][ar] = av.z;
            As[ak + 3][ar] = av.w;
            int br = idx >> 5, bc = (idx & 31) * 4;
            *(float4*)&Bs[br][bc] =
                *(const float4*)&B[(size_t)(k0 + br) * N + n0 + bc];
        }
        __syncthreads();
#pragma unroll
        for (int kk = 0; kk < 16; ++kk) {
            float a[8], bv[8];
            *(float4*)&a[0] = *(const float4*)&As[kk][ty * 8];
            *(float4*)&a[4] = *(const float4*)&As[kk][ty * 8 + 4];
            *(float4*)&bv[0] = *(const float4*)&Bs[kk][tx * 8];
            *(float4*)&bv[4] = *(const float4*)&Bs[kk][tx * 8 + 4];
#pragma unroll
            for (int i = 0; i < 8; ++i)
#pragma unroll
                for (int j = 0; j < 8; ++j)
                    acc[i][j] = fmaf(a[i], bv[j], acc[i][j]);
        }
        __syncthreads();
    }

#pragma unroll
    for (int i = 0; i < 8; ++i) {
        size_t row = (size_t)(m0 + ty * 8 + i);
#pragma unroll
        for (int j4 = 0; j4 < 8; j4 += 4) {
            int col = n0 + tx * 8 + j4;
            float4 o;
            o.x = acc[i][j4 + 0] + bias[col + 0];
            o.y = acc[i][j4 + 1] + bias[col + 1];
            o.z = acc[i][j4 + 2] + bias[col + 2];
            o.w = acc[i][j4 + 3] + bias[col + 3];
            *(float4*)&Cmat[row * N + col] = o;
        }
    }
}

// ---------------------------------------------------------------------------
// Fused RoPE + bf16 convert + V transpose.
// Block = (ttile, bh). q rope'd in place (fp32). k rope'd -> Kb[bh][t][64] bf16.
// v -> Vt[bh][64][t] bf16 (transposed via LDS so attn V-fragments are
// lane-affine for global_load_lds).
// ---------------------------------------------------------------------------
__global__ __launch_bounds__(256) void ropecvt(
    float* qkv, __bf16* __restrict__ Kb, __bf16* __restrict__ Vt)
{
    __shared__ float vt[64][65];
    const int tid = threadIdx.x;
    const int tt = blockIdx.x;
    const int bh = blockIdx.y;
    const int b = bh >> 4, h = bh & 15;
    const int t0 = tt * 64;
    float* base = qkv + ((size_t)(b * T_DIM + t0)) * C3_DIM + h * D_DIM;

    // V tile -> LDS (coalesced)
    const int tx = tid & 15, ty = tid >> 4;
#pragma unroll
    for (int it = 0; it < 4; ++it) {
        int r = it * 16 + ty;
        *(float4*)&vt[r][tx * 4] =
            *(const float4*)&base[(size_t)r * C3_DIM + 2 * C_DIM + tx * 4];
    }

    // RoPE on q (in place, fp32) and k (-> Kb bf16)
#pragma unroll
    for (int p = 0; p < 8; ++p) {
        int idx = tid + p * 256;          // 0..2047 = 64 t x 32 pairs
        int tl = idx >> 5, i = idx & 31;
        float theta = powf(10000.0f, -(float)i / 32.0f);
        float ang = (float)(t0 + tl) * theta;
        float s, c;
        sincosf(ang, &s, &c);
        float* qp = &base[(size_t)tl * C3_DIM + 2 * i];
        float2 q2 = *(float2*)qp;
        float2 qo = { q2.x * c - q2.y * s, q2.x * s + q2.y * c };
        *(float2*)qp = qo;
        float2 k2 = *(float2*)(qp + C_DIM);
        __bf16* kbp = Kb + ((size_t)bh * T_DIM + t0 + tl) * D_DIM + 2 * i;
        kbp[0] = (__bf16)(k2.x * c - k2.y * s);
        kbp[1] = (__bf16)(k2.x * s + k2.y * c);
    }

    __syncthreads();

    // Vt rows (d-major) <- LDS columns; coalesced 32B per lane global writes
    int dd = tid >> 2, tc0 = (tid & 3) * 16;
    __align__(16) __bf16 tmp[16];
#pragma unroll
    for (int j = 0; j < 16; ++j) tmp[j] = (__bf16)vt[tc0 + j][dd];
    __bf16* vo = Vt + ((size_t)bh * D_DIM + dd) * T_DIM + t0 + tc0;
    *(bf16x8*)vo = *(bf16x8*)&tmp[0];
    *(bf16x8*)(vo + 8) = *(bf16x8*)&tmp[8];
}

// ---------------------------------------------------------------------------
// MFMA flash attention, bf16 inputs / fp32 softmax+accum.
// Block = 4 waves = 64 q-rows; wave owns 16 rows. K/V staged into
// fragment-order LDS via global_load_lds dwordx4. P LDS round-trip per wave.
// y written into the dead k-slice columns of qkv (yout = qkv + 1024).
// ---------------------------------------------------------------------------
__global__ __launch_bounds__(256) void attn_mfma(
    const float* qkv, const __bf16* __restrict__ Kb,
    const __bf16* __restrict__ Vt, float* yout)
{
    __shared__ __align__(16) __bf16 Qf[8][64][8];   // [w*2+kc][lane][i]
    __shared__ __align__(16) __bf16 Kf[8][64][8];   // [nb*2+kc][lane][i]
    __shared__ __align__(16) __bf16 Vf[8][64][8];   // [nb*2+kc][lane][i]
    __shared__ __align__(16) __bf16 Pb[4][16][72];  // per-wave P buffer

    const int tid = threadIdx.x;
    const int qt = gridDim.x - 1 - blockIdx.x;   // heavy blocks dispatch first
    const int bh = blockIdx.y;
    const int b = bh >> 4, h = bh & 15;
    const int lane = tid & 63, w = tid >> 6;
    const int m = lane & 15, qq = lane >> 4;

    // ---- stage Q (fp32 -> bf16, pre-scaled by 1/sqrt(D)) into frag layout
    {
        const int tx = tid & 15, ty = tid >> 4;
        const float* qbase =
            qkv + ((size_t)(b * T_DIM + qt * 64)) * C3_DIM + h * D_DIM;
#pragma unroll
        for (int it = 0; it < 4; ++it) {
            int r = it * 16 + ty;            // frag g = it, r&15 = ty
            int d0 = tx * 4;
            float4 v = *(const float4*)&qbase[(size_t)r * C3_DIM + d0];
            bf16x4 o;
            o[0] = (__bf16)(v.x * 0.125f);
            o[1] = (__bf16)(v.y * 0.125f);
            o[2] = (__bf16)(v.z * 0.125f);
            o[3] = (__bf16)(v.w * 0.125f);
            int lf = ((d0 >> 3) & 3) * 16 + ty;
            *(bf16x4*)&Qf[it * 2 + (d0 >> 5)][lf][d0 & 7] = o;
        }
    }
    __syncthreads();

    bf16x8 qreg[2];
    qreg[0] = *(const bf16x8*)&Qf[w * 2 + 0][lane][0];
    qreg[1] = *(const bf16x8*)&Qf[w * 2 + 1][lane][0];

    float m_i[4], l_i[4];
    f32x4 acc[4];
#pragma unroll
    for (int r = 0; r < 4; ++r) { m_i[r] = -1e30f; l_i[r] = 0.f; }
#pragma unroll
    for (int nb = 0; nb < 4; ++nb) acc[nb] = (f32x4){0.f, 0.f, 0.f, 0.f};

    const __bf16* kgbase = Kb + (size_t)bh * T_DIM * D_DIM;
    const __bf16* vgbase = Vt + (size_t)bh * D_DIM * T_DIM;

    for (int kt = 0; kt <= qt; ++kt) {
        __syncthreads();   // all waves done reading Kf/Vf of prev iter
        // ---- DMA stage K,V fragments (wave w stages nb=w; c = kc)
#pragma unroll
        for (int c = 0; c < 2; ++c) {
            const __bf16* kg = kgbase +
                ((size_t)(kt * 64 + w * 16 + m)) * D_DIM + c * 32 + qq * 8;
            __builtin_amdgcn_global_load_lds(
                (gptr_t)(const void*)kg,
                (lptr_t)(void*)&Kf[w * 2 + c][0][0], 16, 0, 0);
            const __bf16* vg = vgbase +
                ((size_t)(w * 16 + m)) * T_DIM + kt * 64 + c * 32 + qq * 8;
            __builtin_amdgcn_global_load_lds(
                (gptr_t)(const void*)vg,
                (lptr_t)(void*)&Vf[w * 2 + c][0][0], 16, 0, 0);
        }
        __syncthreads();   // staging visible

        // ---- S = Q @ K^T (rows qq*4+r, cols nb*16+m)
        f32x4 sv[4];
#pragma unroll
        for (int nb = 0; nb < 4; ++nb) {
            f32x4 s = (f32x4){0.f, 0.f, 0.f, 0.f};
            s = __builtin_amdgcn_mfma_f32_16x16x32_bf16(
                qreg[0], *(const bf16x8*)&Kf[nb * 2 + 0][lane][0], s, 0, 0, 0);
            s = __builtin_amdgcn_mfma_f32_16x16x32_bf16(
                qreg[1], *(const bf16x8*)&Kf[nb * 2 + 1][lane][0], s, 0, 0, 0);
            sv[nb] = s;
        }

        // ---- causal mask (diagonal tile only)
        if (kt == qt) {
            int rowb = w * 16 + qq * 4;
#pragma unroll
            for (int nb = 0; nb < 4; ++nb) {
                int col = nb * 16 + m;
#pragma unroll
                for (int r = 0; r < 4; ++r)
                    if (col > rowb + r) sv[nb][r] = -1e30f;
            }
        }

        // ---- online softmax (row reduce across the 16 lanes of a quad-group)
        float al[4];
#pragma unroll
        for (int r = 0; r < 4; ++r) {
            float mt = fmaxf(fmaxf(sv[0][r], sv[1][r]),
                             fmaxf(sv[2][r], sv[3][r]));
            mt = fmaxf(mt, __shfl_xor(mt, 1));
            mt = fmaxf(mt, __shfl_xor(mt, 2));
            mt = fmaxf(mt, __shfl_xor(mt, 4));
            mt = fmaxf(mt, __shfl_xor(mt, 8));
            float mnew = fmaxf(m_i[r], mt);
            float alpha = __expf(m_i[r] - mnew);
            float ll = 0.f;
#pragma unroll
            for (int nb = 0; nb < 4; ++nb) {
                float p = __expf(sv[nb][r] - mnew);
                sv[nb][r] = p;
                ll += p;
            }
            ll += __shfl_xor(ll, 1);
            ll += __shfl_xor(ll, 2);
            ll += __shfl_xor(ll, 4);
            ll += __shfl_xor(ll, 8);
            l_i[r] = l_i[r] * alpha + ll;
            m_i[r] = mnew;
            al[r] = alpha;
        }
#pragma unroll
        for (int nb = 0; nb < 4; ++nb)
#pragma unroll
            for (int r = 0; r < 4; ++r) acc[nb][r] *= al[r];

        // ---- P: C-layout -> LDS -> A-fragment layout (per-wave, no barrier)
#pragma unroll
        for (int nb = 0; nb < 4; ++nb)
#pragma unroll
            for (int r = 0; r < 4; ++r)
                Pb[w][qq * 4 + r][nb * 16 + m] = (__bf16)sv[nb][r];

        bf16x8 pf0 = *(const bf16x8*)&Pb[w][m][0 * 32 + qq * 8];
        bf16x8 pf1 = *(const bf16x8*)&Pb[w][m][1 * 32 + qq * 8];

        // ---- O += P @ V (cols nb*16+m = d)
#pragma unroll
        for (int nb = 0; nb < 4; ++nb) {
            acc[nb] = __builtin_amdgcn_mfma_f32_16x16x32_bf16(
                pf0, *(const bf16x8*)&Vf[nb * 2 + 0][lane][0], acc[nb], 0, 0, 0);
            acc[nb] = __builtin_amdgcn_mfma_f32_16x16x32_bf16(
                pf1, *(const bf16x8*)&Vf[nb * 2 + 1][lane][0], acc[nb], 0, 0, 0);
        }
    }

    // ---- epilogue: normalize, write y into qkv k-slice (yout = qkv + 1024)
    size_t row0 = (size_t)(b * T_DIM + qt * 64 + w * 16 + qq * 4);
#pragma unroll
    for (int r = 0; r < 4; ++r) {
        float inv = 1.0f / l_i[r];
#pragma unroll
        for (int nb = 0; nb < 4; ++nb)
            yout[(row0 + r) * C3_DIM + h * D_DIM + nb * 16 + m] =
                acc[nb][r] * inv;
    }
}

// ---------------------------------------------------------------------------
extern "C" void kernel_launch(void* const* d_in, const int* in_sizes, int n_in,
                              void* d_out, int out_size, void* d_ws, size_t ws_size,
                              hipStream_t stream)
{
    const float* x     = (const float*)d_in[0];
    const float* Wqkv  = (const float*)d_in[1];
    const float* bqkv  = (const float*)d_in[2];
    const float* Wproj = (const float*)d_in[3];
    const float* bproj = (const float*)d_in[4];
    float* out = (float*)d_out;

    // ws layout (128 MB total):
    //   [0,   96M): qkv fp32 (B,T,3C); k-slice columns reused for y after attn
    //   [96M,112M): Kb bf16 [bh][t][64]
    //   [112M,128M): Vt bf16 [bh][64][t]
    float* qkv = (float*)d_ws;
    __bf16* Kb = (__bf16*)((char*)d_ws + 100663296ull);
    __bf16* Vt = (__bf16*)((char*)d_ws + 117440512ull);

    dim3 blk(256);

    // qkv = x @ W_qkv + b_qkv
    sgemm_bias<<<dim3(C3_DIM / 128, (B_DIM * T_DIM) / 128), blk, 0, stream>>>(
        x, Wqkv, bqkv, qkv, B_DIM * T_DIM, C3_DIM, C_DIM, C_DIM);

    // RoPE q in place; K -> bf16; V -> bf16 transposed
    ropecvt<<<dim3(T_DIM / 64, B_DIM * H_DIM), blk, 0, stream>>>(qkv, Kb, Vt);

    // MFMA flash attention -> y (in qkv k-slice)
    attn_mfma<<<dim3(T_DIM / 64, B_DIM * H_DIM), blk, 0, stream>>>(
        qkv, Kb, Vt, qkv + C_DIM);

    // out = y @ W_proj + b_proj  (A read strided out of qkv)
    sgemm_bias<<<dim3(C_DIM / 128, (B_DIM * T_DIM) / 128), blk, 0, stream>>>(
        qkv + C_DIM, Wproj, bproj, out, B_DIM * T_DIM, C_DIM, C_DIM, C3_DIM);
}

// Round 3
// 446.684 us; speedup vs baseline: 3.9824x; 2.4219x over previous
//
#include <hip/hip_runtime.h>
#include <cstddef>

#define B_DIM 4
#define T_DIM 2048
#define C_DIM 1024
#define H_DIM 16
#define D_DIM 64
#define C3_DIM 3072

typedef __attribute__((ext_vector_type(8))) __bf16 bf16x8;
typedef __attribute__((ext_vector_type(4))) __bf16 bf16x4;
typedef __attribute__((ext_vector_type(2))) __bf16 bf16x2;
typedef __attribute__((ext_vector_type(4))) float f32x4;

typedef const __attribute__((address_space(1))) unsigned int* gptr_t;
typedef __attribute__((address_space(3))) unsigned int* lptr_t;

// ---------------------------------------------------------------------------
// fp32 -> bf16 elementwise (4 elems/thread)
// ---------------------------------------------------------------------------
__global__ __launch_bounds__(256) void cvt_bf16(const float* __restrict__ in,
                                                __bf16* __restrict__ out)
{
    int i = (blockIdx.x * 256 + threadIdx.x) * 4;
    float4 v = *(const float4*)&in[i];
    bf16x4 o = { (__bf16)v.x, (__bf16)v.y, (__bf16)v.z, (__bf16)v.w };
    *(bf16x4*)&out[i] = o;
}

// ---------------------------------------------------------------------------
// W[K][N] fp32 -> Wt[N][K] bf16 (64x64 LDS tile transpose)
// ---------------------------------------------------------------------------
__global__ __launch_bounds__(256) void transpose_cvt(
    const float* __restrict__ W, __bf16* __restrict__ Wt, int K, int N)
{
    __shared__ float tile[64][65];
    const int tid = threadIdx.x;
    const int n0 = blockIdx.x * 64, k0 = blockIdx.y * 64;
    const int tx = tid & 15, ty = tid >> 4;
#pragma unroll
    for (int it = 0; it < 4; ++it) {
        int r = it * 16 + ty;
        *(float4*)&tile[r][tx * 4] =
            *(const float4*)&W[(size_t)(k0 + r) * N + n0 + tx * 4];
    }
    __syncthreads();
    int c = tid >> 2, t0 = (tid & 3) * 16;
    __align__(16) __bf16 tmp[16];
#pragma unroll
    for (int j = 0; j < 16; ++j) tmp[j] = (__bf16)tile[t0 + j][c];
    __bf16* o = Wt + (size_t)(n0 + c) * K + k0 + t0;
    *(bf16x8*)o = *(bf16x8*)&tmp[0];
    *(bf16x8*)(o + 8) = *(bf16x8*)&tmp[8];
}

// ---------------------------------------------------------------------------
// bf16 MFMA GEMM (m97 structure): C[M,N] = A[M,K] @ Bt[N,K]^T + bias[N].
// 128x128 tile, BK=32, 256 threads / 4 waves, 4x4 16x16x32 frags per wave.
// All staging via global_load_lds width=16 into fragment-order LDS.
// ---------------------------------------------------------------------------
template <bool OUT_BF16>
__global__ __launch_bounds__(256) void gemm_bt(
    const __bf16* __restrict__ A, const __bf16* __restrict__ Bt,
    const float* __restrict__ bias, void* __restrict__ Cout,
    int M, int N, int K)
{
    __shared__ __align__(16) __bf16 Af[8][64][8];
    __shared__ __align__(16) __bf16 Bf[8][64][8];
    const int tid = threadIdx.x;
    const int lane = tid & 63, w = tid >> 6;
    const int lm = lane & 15, lq = lane >> 4;
    const int wm = w >> 1, wn = w & 1;
    const int m0 = blockIdx.y * 128, n0 = blockIdx.x * 128;

    // wave w stages A row-blocks {2w,2w+1} and B col-blocks {2w,2w+1}
    const __bf16* a0 = A + (size_t)(m0 + w * 32 + lm) * K + lq * 8;
    const __bf16* a1 = a0 + (size_t)16 * K;
    const __bf16* b0 = Bt + (size_t)(n0 + w * 32 + lm) * K + lq * 8;
    const __bf16* b1 = b0 + (size_t)16 * K;

    f32x4 acc[4][4];
#pragma unroll
    for (int i = 0; i < 4; ++i)
#pragma unroll
        for (int j = 0; j < 4; ++j) acc[i][j] = (f32x4){0.f, 0.f, 0.f, 0.f};

    for (int k0 = 0; k0 < K; k0 += 32) {
        __syncthreads();
        __builtin_amdgcn_global_load_lds((gptr_t)(const void*)(a0 + k0),
                                         (lptr_t)(void*)&Af[w * 2 + 0][0][0], 16, 0, 0);
        __builtin_amdgcn_global_load_lds((gptr_t)(const void*)(a1 + k0),
                                         (lptr_t)(void*)&Af[w * 2 + 1][0][0], 16, 0, 0);
        __builtin_amdgcn_global_load_lds((gptr_t)(const void*)(b0 + k0),
                                         (lptr_t)(void*)&Bf[w * 2 + 0][0][0], 16, 0, 0);
        __builtin_amdgcn_global_load_lds((gptr_t)(const void*)(b1 + k0),
                                         (lptr_t)(void*)&Bf[w * 2 + 1][0][0], 16, 0, 0);
        __syncthreads();

        bf16x8 av[4], bv[4];
#pragma unroll
        for (int i = 0; i < 4; ++i) {
            av[i] = *(const bf16x8*)&Af[wm * 4 + i][lane][0];
            bv[i] = *(const bf16x8*)&Bf[wn * 4 + i][lane][0];
        }
#pragma unroll
        for (int i = 0; i < 4; ++i)
#pragma unroll
            for (int j = 0; j < 4; ++j)
                acc[i][j] = __builtin_amdgcn_mfma_f32_16x16x32_bf16(
                    av[i], bv[j], acc[i][j], 0, 0, 0);
    }

#pragma unroll
    for (int i = 0; i < 4; ++i) {
        int rowb = m0 + wm * 64 + i * 16 + lq * 4;
#pragma unroll
        for (int j = 0; j < 4; ++j) {
            int col = n0 + wn * 64 + j * 16 + lm;
            float bcol = bias[col];
#pragma unroll
            for (int r = 0; r < 4; ++r) {
                float v = acc[i][j][r] + bcol;
                if (OUT_BF16)
                    ((__bf16*)Cout)[(size_t)(rowb + r) * N + col] = (__bf16)v;
                else
                    ((float*)Cout)[(size_t)(rowb + r) * N + col] = v;
            }
        }
    }
}

// ---------------------------------------------------------------------------
// RoPE on bf16 qkv: q rope'd *0.125 in place; k rope'd -> Kb[bh][t][64];
// v -> Vt[bh][64][t] (LDS transpose).
// ---------------------------------------------------------------------------
__global__ __launch_bounds__(256) void ropecvt(
    __bf16* qkv, __bf16* __restrict__ Kb, __bf16* __restrict__ Vt)
{
    __shared__ __bf16 vt[64][72];
    const int tid = threadIdx.x;
    const int t0 = blockIdx.x * 64;
    const int bh = blockIdx.y;
    const int b = bh >> 4, h = bh & 15;
    __bf16* base = qkv + ((size_t)(b * T_DIM + t0)) * C3_DIM + h * D_DIM;

    // V tile -> LDS
    {
        int rr = tid >> 3, cc = (tid & 7) * 8;
#pragma unroll
        for (int it = 0; it < 2; ++it) {
            int r = it * 32 + rr;
            *(bf16x8*)&vt[r][cc] =
                *(const bf16x8*)&base[(size_t)r * C3_DIM + 2 * C_DIM + cc];
        }
    }

    // RoPE q (in place, pre-scaled) and k (-> Kb)
#pragma unroll
    for (int p = 0; p < 8; ++p) {
        int idx = tid + p * 256;          // 64 t x 32 pairs
        int tl = idx >> 5, i = idx & 31;
        float theta = powf(10000.0f, -(float)i / 32.0f);
        float ang = (float)(t0 + tl) * theta;
        float s, c;
        sincosf(ang, &s, &c);
        __bf16* qp = &base[(size_t)tl * C3_DIM + 2 * i];
        float qx = (float)qp[0], qy = (float)qp[1];
        bf16x2 qo = { (__bf16)((qx * c - qy * s) * 0.125f),
                      (__bf16)((qx * s + qy * c) * 0.125f) };
        *(bf16x2*)qp = qo;
        float kx = (float)qp[C_DIM], ky = (float)qp[C_DIM + 1];
        bf16x2 ko = { (__bf16)(kx * c - ky * s), (__bf16)(kx * s + ky * c) };
        *(bf16x2*)(Kb + ((size_t)bh * T_DIM + t0 + tl) * D_DIM + 2 * i) = ko;
    }

    __syncthreads();

    int dd = tid >> 2, tc0 = (tid & 3) * 16;
    __align__(16) __bf16 tmp[16];
#pragma unroll
    for (int j = 0; j < 16; ++j) tmp[j] = vt[tc0 + j][dd];
    __bf16* vo = Vt + ((size_t)bh * D_DIM + dd) * T_DIM + t0 + tc0;
    *(bf16x8*)vo = *(bf16x8*)&tmp[0];
    *(bf16x8*)(vo + 8) = *(bf16x8*)&tmp[8];
}

// ---------------------------------------------------------------------------
// MFMA flash attention (bf16 in / fp32 softmax+accum), unchanged structure
// from R2 except: Q staged by DMA (pre-scaled in ropecvt), output -> compact
// bf16 yb[M][C].
// ---------------------------------------------------------------------------
__global__ __launch_bounds__(256) void attn_mfma(
    const __bf16* __restrict__ qkvb, const __bf16* __restrict__ Kb,
    const __bf16* __restrict__ Vt, __bf16* __restrict__ yb)
{
    __shared__ __align__(16) __bf16 Qf[8][64][8];
    __shared__ __align__(16) __bf16 Kf[8][64][8];
    __shared__ __align__(16) __bf16 Vf[8][64][8];
    __shared__ __align__(16) __bf16 Pb[4][16][72];

    const int tid = threadIdx.x;
    const int qt = gridDim.x - 1 - blockIdx.x;   // heavy blocks first
    const int bh = blockIdx.y;
    const int b = bh >> 4, h = bh & 15;
    const int lane = tid & 63, w = tid >> 6;
    const int m = lane & 15, qq = lane >> 4;

    // ---- stage Q fragments via DMA (already rope'd + 1/sqrt(D) scaled)
    {
        const __bf16* qg = qkvb +
            ((size_t)(b * T_DIM + qt * 64 + w * 16 + m)) * C3_DIM +
            h * D_DIM + qq * 8;
        __builtin_amdgcn_global_load_lds((gptr_t)(const void*)qg,
                                         (lptr_t)(void*)&Qf[w * 2 + 0][0][0], 16, 0, 0);
        __builtin_amdgcn_global_load_lds((gptr_t)(const void*)(qg + 32),
                                         (lptr_t)(void*)&Qf[w * 2 + 1][0][0], 16, 0, 0);
    }
    __syncthreads();

    bf16x8 qreg[2];
    qreg[0] = *(const bf16x8*)&Qf[w * 2 + 0][lane][0];
    qreg[1] = *(const bf16x8*)&Qf[w * 2 + 1][lane][0];

    float m_i[4], l_i[4];
    f32x4 acc[4];
#pragma unroll
    for (int r = 0; r < 4; ++r) { m_i[r] = -1e30f; l_i[r] = 0.f; }
#pragma unroll
    for (int nb = 0; nb < 4; ++nb) acc[nb] = (f32x4){0.f, 0.f, 0.f, 0.f};

    const __bf16* kgbase = Kb + (size_t)bh * T_DIM * D_DIM;
    const __bf16* vgbase = Vt + (size_t)bh * D_DIM * T_DIM;

    for (int kt = 0; kt <= qt; ++kt) {
        __syncthreads();
#pragma unroll
        for (int c = 0; c < 2; ++c) {
            const __bf16* kg = kgbase +
                ((size_t)(kt * 64 + w * 16 + m)) * D_DIM + c * 32 + qq * 8;
            __builtin_amdgcn_global_load_lds(
                (gptr_t)(const void*)kg,
                (lptr_t)(void*)&Kf[w * 2 + c][0][0], 16, 0, 0);
            const __bf16* vg = vgbase +
                ((size_t)(w * 16 + m)) * T_DIM + kt * 64 + c * 32 + qq * 8;
            __builtin_amdgcn_global_load_lds(
                (gptr_t)(const void*)vg,
                (lptr_t)(void*)&Vf[w * 2 + c][0][0], 16, 0, 0);
        }
        __syncthreads();

        // ---- S = Q @ K^T
        f32x4 sv[4];
#pragma unroll
        for (int nb = 0; nb < 4; ++nb) {
            f32x4 s = (f32x4){0.f, 0.f, 0.f, 0.f};
            s = __builtin_amdgcn_mfma_f32_16x16x32_bf16(
                qreg[0], *(const bf16x8*)&Kf[nb * 2 + 0][lane][0], s, 0, 0, 0);
            s = __builtin_amdgcn_mfma_f32_16x16x32_bf16(
                qreg[1], *(const bf16x8*)&Kf[nb * 2 + 1][lane][0], s, 0, 0, 0);
            sv[nb] = s;
        }

        if (kt == qt) {
            int rowb = w * 16 + qq * 4;
#pragma unroll
            for (int nb = 0; nb < 4; ++nb) {
                int col = nb * 16 + m;
#pragma unroll
                for (int r = 0; r < 4; ++r)
                    if (col > rowb + r) sv[nb][r] = -1e30f;
            }
        }

        float al[4];
#pragma unroll
        for (int r = 0; r < 4; ++r) {
            float mt = fmaxf(fmaxf(sv[0][r], sv[1][r]),
                             fmaxf(sv[2][r], sv[3][r]));
            mt = fmaxf(mt, __shfl_xor(mt, 1));
            mt = fmaxf(mt, __shfl_xor(mt, 2));
            mt = fmaxf(mt, __shfl_xor(mt, 4));
            mt = fmaxf(mt, __shfl_xor(mt, 8));
            float mnew = fmaxf(m_i[r], mt);
            float alpha = __expf(m_i[r] - mnew);
            float ll = 0.f;
#pragma unroll
            for (int nb = 0; nb < 4; ++nb) {
                float p = __expf(sv[nb][r] - mnew);
                sv[nb][r] = p;
                ll += p;
            }
            ll += __shfl_xor(ll, 1);
            ll += __shfl_xor(ll, 2);
            ll += __shfl_xor(ll, 4);
            ll += __shfl_xor(ll, 8);
            l_i[r] = l_i[r] * alpha + ll;
            m_i[r] = mnew;
            al[r] = alpha;
        }
#pragma unroll
        for (int nb = 0; nb < 4; ++nb)
#pragma unroll
            for (int r = 0; r < 4; ++r) acc[nb][r] *= al[r];

        // ---- P: C-layout -> per-wave LDS -> A-fragment layout
#pragma unroll
        for (int nb = 0; nb < 4; ++nb)
#pragma unroll
            for (int r = 0; r < 4; ++r)
                Pb[w][qq * 4 + r][nb * 16 + m] = (__bf16)sv[nb][r];

        bf16x8 pf0 = *(const bf16x8*)&Pb[w][m][0 * 32 + qq * 8];
        bf16x8 pf1 = *(const bf16x8*)&Pb[w][m][1 * 32 + qq * 8];

#pragma unroll
        for (int nb = 0; nb < 4; ++nb) {
            acc[nb] = __builtin_amdgcn_mfma_f32_16x16x32_bf16(
                pf0, *(const bf16x8*)&Vf[nb * 2 + 0][lane][0], acc[nb], 0, 0, 0);
            acc[nb] = __builtin_amdgcn_mfma_f32_16x16x32_bf16(
                pf1, *(const bf16x8*)&Vf[nb * 2 + 1][lane][0], acc[nb], 0, 0, 0);
        }
    }

    size_t row0 = (size_t)(b * T_DIM + qt * 64 + w * 16 + qq * 4);
#pragma unroll
    for (int r = 0; r < 4; ++r) {
        float inv = 1.0f / l_i[r];
#pragma unroll
        for (int nb = 0; nb < 4; ++nb)
            yb[(row0 + r) * C_DIM + h * D_DIM + nb * 16 + m] =
                (__bf16)(acc[nb][r] * inv);
    }
}

// ---------------------------------------------------------------------------
extern "C" void kernel_launch(void* const* d_in, const int* in_sizes, int n_in,
                              void* d_out, int out_size, void* d_ws, size_t ws_size,
                              hipStream_t stream)
{
    const float* x     = (const float*)d_in[0];
    const float* Wqkv  = (const float*)d_in[1];
    const float* bqkv  = (const float*)d_in[2];
    const float* Wproj = (const float*)d_in[3];
    const float* bproj = (const float*)d_in[4];
    float* out = (float*)d_out;

    // ws layout (120 MB):
    char* ws = (char*)d_ws;
    __bf16* qkvb = (__bf16*)(ws);                        // [8192][3072] 48 MB
    __bf16* xb   = (__bf16*)(ws + 50331648ull);          // [8192][1024] 16 MB
    __bf16* yb   = (__bf16*)(ws + 67108864ull);          // [8192][1024] 16 MB
    __bf16* Kb   = (__bf16*)(ws + 83886080ull);          // [64][2048][64] 16 MB
    __bf16* Vt   = (__bf16*)(ws + 100663296ull);         // [64][64][2048] 16 MB
    __bf16* Wqt  = (__bf16*)(ws + 117440512ull);         // [3072][1024] 6 MB
    __bf16* Wpt  = (__bf16*)(ws + 123731968ull);         // [1024][1024] 2 MB

    dim3 blk(256);

    // x -> bf16; W -> bf16 transposed
    cvt_bf16<<<dim3((B_DIM * T_DIM * C_DIM) / 1024), blk, 0, stream>>>(x, xb);
    transpose_cvt<<<dim3(C3_DIM / 64, C_DIM / 64), blk, 0, stream>>>(
        Wqkv, Wqt, C_DIM, C3_DIM);
    transpose_cvt<<<dim3(C_DIM / 64, C_DIM / 64), blk, 0, stream>>>(
        Wproj, Wpt, C_DIM, C_DIM);

    // qkvb = xb @ Wqkv^T + b_qkv  (bf16 out)
    gemm_bt<true><<<dim3(C3_DIM / 128, (B_DIM * T_DIM) / 128), blk, 0, stream>>>(
        xb, Wqt, bqkv, qkvb, B_DIM * T_DIM, C3_DIM, C_DIM);

    // RoPE q in place (pre-scaled); K,V repack
    ropecvt<<<dim3(T_DIM / 64, B_DIM * H_DIM), blk, 0, stream>>>(qkvb, Kb, Vt);

    // attention -> yb bf16
    attn_mfma<<<dim3(T_DIM / 64, B_DIM * H_DIM), blk, 0, stream>>>(
        qkvb, Kb, Vt, yb);

    // out = yb @ Wproj^T + b_proj  (fp32 out)
    gemm_bt<false><<<dim3(C_DIM / 128, (B_DIM * T_DIM) / 128), blk, 0, stream>>>(
        yb, Wpt, bproj, out, B_DIM * T_DIM, C_DIM, C_DIM);
}

// Round 4
// 374.265 us; speedup vs baseline: 4.7530x; 1.1935x over previous
//
#include <hip/hip_runtime.h>
#include <cstddef>

#define B_DIM 4
#define T_DIM 2048
#define C_DIM 1024
#define H_DIM 16
#define D_DIM 64
#define C3_DIM 3072

typedef __attribute__((ext_vector_type(8))) __bf16 bf16x8;
typedef __attribute__((ext_vector_type(4))) __bf16 bf16x4;
typedef __attribute__((ext_vector_type(2))) __bf16 bf16x2;
typedef __attribute__((ext_vector_type(4))) float f32x4;

typedef const __attribute__((address_space(1))) unsigned int* gptr_t;
typedef __attribute__((address_space(3))) unsigned int* lptr_t;

// ---------------------------------------------------------------------------
// fp32 -> bf16 elementwise (4 elems/thread)
// ---------------------------------------------------------------------------
__global__ __launch_bounds__(256) void cvt_bf16(const float* __restrict__ in,
                                                __bf16* __restrict__ out)
{
    int i = (blockIdx.x * 256 + threadIdx.x) * 4;
    float4 v = *(const float4*)&in[i];
    bf16x4 o = { (__bf16)v.x, (__bf16)v.y, (__bf16)v.z, (__bf16)v.w };
    *(bf16x4*)&out[i] = o;
}

// ---------------------------------------------------------------------------
// W[K][N] fp32 -> Wt[N][K] bf16 (64x64 LDS tile transpose)
// ---------------------------------------------------------------------------
__global__ __launch_bounds__(256) void transpose_cvt(
    const float* __restrict__ W, __bf16* __restrict__ Wt, int K, int N)
{
    __shared__ float tile[64][65];
    const int tid = threadIdx.x;
    const int n0 = blockIdx.x * 64, k0 = blockIdx.y * 64;
    const int tx = tid & 15, ty = tid >> 4;
#pragma unroll
    for (int it = 0; it < 4; ++it) {
        int r = it * 16 + ty;
        *(float4*)&tile[r][tx * 4] =
            *(const float4*)&W[(size_t)(k0 + r) * N + n0 + tx * 4];
    }
    __syncthreads();
    int c = tid >> 2, t0 = (tid & 3) * 16;
    __align__(16) __bf16 tmp[16];
#pragma unroll
    for (int j = 0; j < 16; ++j) tmp[j] = (__bf16)tile[t0 + j][c];
    __bf16* o = Wt + (size_t)(n0 + c) * K + k0 + t0;
    *(bf16x8*)o = *(bf16x8*)&tmp[0];
    *(bf16x8*)(o + 8) = *(bf16x8*)&tmp[8];
}

// ---------------------------------------------------------------------------
// bf16 MFMA GEMM (m97 structure): C[M,N] = A[M,K] @ Bt[N,K]^T + bias[N].
// 128x128 tile, BK=32, 256 threads / 4 waves, 4x4 16x16x32 frags per wave.
// ---------------------------------------------------------------------------
template <bool OUT_BF16>
__global__ __launch_bounds__(256) void gemm_bt(
    const __bf16* __restrict__ A, const __bf16* __restrict__ Bt,
    const float* __restrict__ bias, void* __restrict__ Cout,
    int M, int N, int K)
{
    __shared__ __align__(16) __bf16 Af[8][64][8];
    __shared__ __align__(16) __bf16 Bf[8][64][8];
    const int tid = threadIdx.x;
    const int lane = tid & 63, w = tid >> 6;
    const int lm = lane & 15, lq = lane >> 4;
    const int wm = w >> 1, wn = w & 1;
    const int m0 = blockIdx.y * 128, n0 = blockIdx.x * 128;

    const __bf16* a0 = A + (size_t)(m0 + w * 32 + lm) * K + lq * 8;
    const __bf16* a1 = a0 + (size_t)16 * K;
    const __bf16* b0 = Bt + (size_t)(n0 + w * 32 + lm) * K + lq * 8;
    const __bf16* b1 = b0 + (size_t)16 * K;

    f32x4 acc[4][4];
#pragma unroll
    for (int i = 0; i < 4; ++i)
#pragma unroll
        for (int j = 0; j < 4; ++j) acc[i][j] = (f32x4){0.f, 0.f, 0.f, 0.f};

    for (int k0 = 0; k0 < K; k0 += 32) {
        __syncthreads();
        __builtin_amdgcn_global_load_lds((gptr_t)(const void*)(a0 + k0),
                                         (lptr_t)(void*)&Af[w * 2 + 0][0][0], 16, 0, 0);
        __builtin_amdgcn_global_load_lds((gptr_t)(const void*)(a1 + k0),
                                         (lptr_t)(void*)&Af[w * 2 + 1][0][0], 16, 0, 0);
        __builtin_amdgcn_global_load_lds((gptr_t)(const void*)(b0 + k0),
                                         (lptr_t)(void*)&Bf[w * 2 + 0][0][0], 16, 0, 0);
        __builtin_amdgcn_global_load_lds((gptr_t)(const void*)(b1 + k0),
                                         (lptr_t)(void*)&Bf[w * 2 + 1][0][0], 16, 0, 0);
        __syncthreads();

        bf16x8 av[4], bv[4];
#pragma unroll
        for (int i = 0; i < 4; ++i) {
            av[i] = *(const bf16x8*)&Af[wm * 4 + i][lane][0];
            bv[i] = *(const bf16x8*)&Bf[wn * 4 + i][lane][0];
        }
#pragma unroll
        for (int i = 0; i < 4; ++i)
#pragma unroll
            for (int j = 0; j < 4; ++j)
                acc[i][j] = __builtin_amdgcn_mfma_f32_16x16x32_bf16(
                    av[i], bv[j], acc[i][j], 0, 0, 0);
    }

#pragma unroll
    for (int i = 0; i < 4; ++i) {
        int rowb = m0 + wm * 64 + i * 16 + lq * 4;
#pragma unroll
        for (int j = 0; j < 4; ++j) {
            int col = n0 + wn * 64 + j * 16 + lm;
            float bcol = bias[col];
#pragma unroll
            for (int r = 0; r < 4; ++r) {
                float v = acc[i][j][r] + bcol;
                if (OUT_BF16)
                    ((__bf16*)Cout)[(size_t)(rowb + r) * N + col] = (__bf16)v;
                else
                    ((float*)Cout)[(size_t)(rowb + r) * N + col] = v;
            }
        }
    }
}

// ---------------------------------------------------------------------------
// RoPE on bf16 qkv: q rope'd * (0.125*log2e) in place (exp2-domain softmax);
// k rope'd -> Kb[bh][t][64]; v -> Vt[bh][64][t] (LDS transpose).
// ---------------------------------------------------------------------------
__global__ __launch_bounds__(256) void ropecvt(
    __bf16* qkv, __bf16* __restrict__ Kb, __bf16* __restrict__ Vt)
{
    __shared__ __bf16 vt[64][72];
    const int tid = threadIdx.x;
    const int t0 = blockIdx.x * 64;
    const int bh = blockIdx.y;
    const int b = bh >> 4, h = bh & 15;
    __bf16* base = qkv + ((size_t)(b * T_DIM + t0)) * C3_DIM + h * D_DIM;

    // V tile -> LDS
    {
        int rr = tid >> 3, cc = (tid & 7) * 8;
#pragma unroll
        for (int it = 0; it < 2; ++it) {
            int r = it * 32 + rr;
            *(bf16x8*)&vt[r][cc] =
                *(const bf16x8*)&base[(size_t)r * C3_DIM + 2 * C_DIM + cc];
        }
    }

    const float QSCALE = 0.125f * 1.44269504089f;  // 1/sqrt(D) * log2(e)

#pragma unroll
    for (int p = 0; p < 8; ++p) {
        int idx = tid + p * 256;          // 64 t x 32 pairs
        int tl = idx >> 5, i = idx & 31;
        float theta = powf(10000.0f, -(float)i / 32.0f);
        float ang = (float)(t0 + tl) * theta;
        float s, c;
        sincosf(ang, &s, &c);
        __bf16* qp = &base[(size_t)tl * C3_DIM + 2 * i];
        float qx = (float)qp[0], qy = (float)qp[1];
        bf16x2 qo = { (__bf16)((qx * c - qy * s) * QSCALE),
                      (__bf16)((qx * s + qy * c) * QSCALE) };
        *(bf16x2*)qp = qo;
        float kx = (float)qp[C_DIM], ky = (float)qp[C_DIM + 1];
        bf16x2 ko = { (__bf16)(kx * c - ky * s), (__bf16)(kx * s + ky * c) };
        *(bf16x2*)(Kb + ((size_t)bh * T_DIM + t0 + tl) * D_DIM + 2 * i) = ko;
    }

    __syncthreads();

    int dd = tid >> 2, tc0 = (tid & 3) * 16;
    __align__(16) __bf16 tmp[16];
#pragma unroll
    for (int j = 0; j < 16; ++j) tmp[j] = vt[tc0 + j][dd];
    __bf16* vo = Vt + ((size_t)bh * D_DIM + dd) * T_DIM + t0 + tc0;
    *(bf16x8*)vo = *(bf16x8*)&tmp[0];
    *(bf16x8*)(vo + 8) = *(bf16x8*)&tmp[8];
}

// ---------------------------------------------------------------------------
// MFMA flash attention v2. Changes vs R3:
//  - Q A-fragments loaded directly from global (no Qf LDS, no Q barrier)
//  - LDS 25.6 KB (Kf+Vf+Pb) -> 6 blocks/CU residency
//  - exp2-domain softmax (Q pre-scaled by log2e/sqrt(D) in ropecvt)
//  - grid (bh, qtile), qt descending: heavy blocks dispatch first
// ---------------------------------------------------------------------------
__global__ __launch_bounds__(256) void attn_mfma(
    const __bf16* __restrict__ qkvb, const __bf16* __restrict__ Kb,
    const __bf16* __restrict__ Vt, __bf16* __restrict__ yb)
{
    __shared__ __align__(16) __bf16 Kf[8][64][8];   // 8 KB
    __shared__ __align__(16) __bf16 Vf[8][64][8];   // 8 KB
    __shared__ __align__(16) __bf16 Pb[4][16][72];  // 9.2 KB

    const int tid = threadIdx.x;
    const int bh = blockIdx.x;                  // 0..63
    const int qt = 31 - blockIdx.y;             // heavy first
    const int b = bh >> 4, h = bh & 15;
    const int lane = tid & 63, w = tid >> 6;
    const int m = lane & 15, qq = lane >> 4;

    // ---- Q fragments: direct global loads (pre-rope'd, pre-scaled)
    const __bf16* qrow = qkvb +
        ((size_t)(b * T_DIM + qt * 64 + w * 16 + m)) * C3_DIM + h * D_DIM + qq * 8;
    bf16x8 qreg[2];
    qreg[0] = *(const bf16x8*)qrow;
    qreg[1] = *(const bf16x8*)(qrow + 32);

    float m_i[4], l_i[4];
    f32x4 acc[4];
#pragma unroll
    for (int r = 0; r < 4; ++r) { m_i[r] = -1e30f; l_i[r] = 0.f; }
#pragma unroll
    for (int nb = 0; nb < 4; ++nb) acc[nb] = (f32x4){0.f, 0.f, 0.f, 0.f};

    const __bf16* kgbase = Kb + (size_t)bh * T_DIM * D_DIM;
    const __bf16* vgbase = Vt + (size_t)bh * D_DIM * T_DIM;

    for (int kt = 0; kt <= qt; ++kt) {
        __syncthreads();   // all waves done reading Kf/Vf of prev iter
#pragma unroll
        for (int c = 0; c < 2; ++c) {
            const __bf16* kg = kgbase +
                ((size_t)(kt * 64 + w * 16 + m)) * D_DIM + c * 32 + qq * 8;
            __builtin_amdgcn_global_load_lds(
                (gptr_t)(const void*)kg,
                (lptr_t)(void*)&Kf[w * 2 + c][0][0], 16, 0, 0);
            const __bf16* vg = vgbase +
                ((size_t)(w * 16 + m)) * T_DIM + kt * 64 + c * 32 + qq * 8;
            __builtin_amdgcn_global_load_lds(
                (gptr_t)(const void*)vg,
                (lptr_t)(void*)&Vf[w * 2 + c][0][0], 16, 0, 0);
        }
        __syncthreads();   // staging visible

        // ---- S = Q @ K^T (exp2 domain)
        f32x4 sv[4];
#pragma unroll
        for (int nb = 0; nb < 4; ++nb) {
            f32x4 s = (f32x4){0.f, 0.f, 0.f, 0.f};
            s = __builtin_amdgcn_mfma_f32_16x16x32_bf16(
                qreg[0], *(const bf16x8*)&Kf[nb * 2 + 0][lane][0], s, 0, 0, 0);
            s = __builtin_amdgcn_mfma_f32_16x16x32_bf16(
                qreg[1], *(const bf16x8*)&Kf[nb * 2 + 1][lane][0], s, 0, 0, 0);
            sv[nb] = s;
        }

        if (kt == qt) {
            int rowb = w * 16 + qq * 4;
#pragma unroll
            for (int nb = 0; nb < 4; ++nb) {
                int col = nb * 16 + m;
#pragma unroll
                for (int r = 0; r < 4; ++r)
                    if (col > rowb + r) sv[nb][r] = -1e30f;
            }
        }

        float al[4];
#pragma unroll
        for (int r = 0; r < 4; ++r) {
            float mt = fmaxf(fmaxf(sv[0][r], sv[1][r]),
                             fmaxf(sv[2][r], sv[3][r]));
            mt = fmaxf(mt, __shfl_xor(mt, 1));
            mt = fmaxf(mt, __shfl_xor(mt, 2));
            mt = fmaxf(mt, __shfl_xor(mt, 4));
            mt = fmaxf(mt, __shfl_xor(mt, 8));
            float mnew = fmaxf(m_i[r], mt);
            float alpha = exp2f(m_i[r] - mnew);
            float ll = 0.f;
#pragma unroll
            for (int nb = 0; nb < 4; ++nb) {
                float p = exp2f(sv[nb][r] - mnew);
                sv[nb][r] = p;
                ll += p;
            }
            ll += __shfl_xor(ll, 1);
            ll += __shfl_xor(ll, 2);
            ll += __shfl_xor(ll, 4);
            ll += __shfl_xor(ll, 8);
            l_i[r] = l_i[r] * alpha + ll;
            m_i[r] = mnew;
            al[r] = alpha;
        }
#pragma unroll
        for (int nb = 0; nb < 4; ++nb)
#pragma unroll
            for (int r = 0; r < 4; ++r) acc[nb][r] *= al[r];

        // ---- P: C-layout -> per-wave LDS -> A-fragment layout
#pragma unroll
        for (int nb = 0; nb < 4; ++nb)
#pragma unroll
            for (int r = 0; r < 4; ++r)
                Pb[w][qq * 4 + r][nb * 16 + m] = (__bf16)sv[nb][r];

        bf16x8 pf0 = *(const bf16x8*)&Pb[w][m][0 * 32 + qq * 8];
        bf16x8 pf1 = *(const bf16x8*)&Pb[w][m][1 * 32 + qq * 8];

#pragma unroll
        for (int nb = 0; nb < 4; ++nb) {
            acc[nb] = __builtin_amdgcn_mfma_f32_16x16x32_bf16(
                pf0, *(const bf16x8*)&Vf[nb * 2 + 0][lane][0], acc[nb], 0, 0, 0);
            acc[nb] = __builtin_amdgcn_mfma_f32_16x16x32_bf16(
                pf1, *(const bf16x8*)&Vf[nb * 2 + 1][lane][0], acc[nb], 0, 0, 0);
        }
    }

    size_t row0 = (size_t)(b * T_DIM + qt * 64 + w * 16 + qq * 4);
#pragma unroll
    for (int r = 0; r < 4; ++r) {
        float inv = 1.0f / l_i[r];
#pragma unroll
        for (int nb = 0; nb < 4; ++nb)
            yb[(row0 + r) * C_DIM + h * D_DIM + nb * 16 + m] =
                (__bf16)(acc[nb][r] * inv);
    }
}

// ---------------------------------------------------------------------------
extern "C" void kernel_launch(void* const* d_in, const int* in_sizes, int n_in,
                              void* d_out, int out_size, void* d_ws, size_t ws_size,
                              hipStream_t stream)
{
    const float* x     = (const float*)d_in[0];
    const float* Wqkv  = (const float*)d_in[1];
    const float* bqkv  = (const float*)d_in[2];
    const float* Wproj = (const float*)d_in[3];
    const float* bproj = (const float*)d_in[4];
    float* out = (float*)d_out;

    char* ws = (char*)d_ws;
    __bf16* qkvb = (__bf16*)(ws);                        // [8192][3072] 48 MB
    __bf16* xb   = (__bf16*)(ws + 50331648ull);          // [8192][1024] 16 MB
    __bf16* yb   = (__bf16*)(ws + 67108864ull);          // [8192][1024] 16 MB
    __bf16* Kb   = (__bf16*)(ws + 83886080ull);          // [64][2048][64] 16 MB
    __bf16* Vt   = (__bf16*)(ws + 100663296ull);         // [64][64][2048] 16 MB
    __bf16* Wqt  = (__bf16*)(ws + 117440512ull);         // [3072][1024] 6 MB
    __bf16* Wpt  = (__bf16*)(ws + 123731968ull);         // [1024][1024] 2 MB

    dim3 blk(256);

    cvt_bf16<<<dim3((B_DIM * T_DIM * C_DIM) / 1024), blk, 0, stream>>>(x, xb);
    transpose_cvt<<<dim3(C3_DIM / 64, C_DIM / 64), blk, 0, stream>>>(
        Wqkv, Wqt, C_DIM, C3_DIM);
    transpose_cvt<<<dim3(C_DIM / 64, C_DIM / 64), blk, 0, stream>>>(
        Wproj, Wpt, C_DIM, C_DIM);

    gemm_bt<true><<<dim3(C3_DIM / 128, (B_DIM * T_DIM) / 128), blk, 0, stream>>>(
        xb, Wqt, bqkv, qkvb, B_DIM * T_DIM, C3_DIM, C_DIM);

    ropecvt<<<dim3(T_DIM / 64, B_DIM * H_DIM), blk, 0, stream>>>(qkvb, Kb, Vt);

    // grid: x = bh (64), y = qtile (32, reversed inside kernel)
    attn_mfma<<<dim3(B_DIM * H_DIM, T_DIM / 64), blk, 0, stream>>>(
        qkvb, Kb, Vt, yb);

    gemm_bt<false><<<dim3(C_DIM / 128, (B_DIM * T_DIM) / 128), blk, 0, stream>>>(
        yb, Wpt, bproj, out, B_DIM * T_DIM, C_DIM, C_DIM);
}

// Round 5
// 341.508 us; speedup vs baseline: 5.2090x; 1.0959x over previous
//
#include <hip/hip_runtime.h>
#include <cstddef>

#define B_DIM 4
#define T_DIM 2048
#define C_DIM 1024
#define H_DIM 16
#define D_DIM 64
#define C3_DIM 3072

typedef __attribute__((ext_vector_type(8))) __bf16 bf16x8;
typedef __attribute__((ext_vector_type(4))) __bf16 bf16x4;
typedef __attribute__((ext_vector_type(2))) __bf16 bf16x2;
typedef __attribute__((ext_vector_type(4))) float f32x4;

typedef const __attribute__((address_space(1))) unsigned int* gptr_t;
typedef __attribute__((address_space(3))) unsigned int* lptr_t;

// ---------------------------------------------------------------------------
// fp32 -> bf16 elementwise (4 elems/thread)
// ---------------------------------------------------------------------------
__global__ __launch_bounds__(256) void cvt_bf16(const float* __restrict__ in,
                                                __bf16* __restrict__ out)
{
    int i = (blockIdx.x * 256 + threadIdx.x) * 4;
    float4 v = *(const float4*)&in[i];
    bf16x4 o = { (__bf16)v.x, (__bf16)v.y, (__bf16)v.z, (__bf16)v.w };
    *(bf16x4*)&out[i] = o;
}

// ---------------------------------------------------------------------------
// W[K][N] fp32 -> Wt[N][K] bf16 (64x64 LDS tile transpose)
// ---------------------------------------------------------------------------
__global__ __launch_bounds__(256) void transpose_cvt(
    const float* __restrict__ W, __bf16* __restrict__ Wt, int K, int N)
{
    __shared__ float tile[64][65];
    const int tid = threadIdx.x;
    const int n0 = blockIdx.x * 64, k0 = blockIdx.y * 64;
    const int tx = tid & 15, ty = tid >> 4;
#pragma unroll
    for (int it = 0; it < 4; ++it) {
        int r = it * 16 + ty;
        *(float4*)&tile[r][tx * 4] =
            *(const float4*)&W[(size_t)(k0 + r) * N + n0 + tx * 4];
    }
    __syncthreads();
    int c = tid >> 2, t0 = (tid & 3) * 16;
    __align__(16) __bf16 tmp[16];
#pragma unroll
    for (int j = 0; j < 16; ++j) tmp[j] = (__bf16)tile[t0 + j][c];
    __bf16* o = Wt + (size_t)(n0 + c) * K + k0 + t0;
    *(bf16x8*)o = *(bf16x8*)&tmp[0];
    *(bf16x8*)(o + 8) = *(bf16x8*)&tmp[8];
}

// ---------------------------------------------------------------------------
// bf16 MFMA GEMM (m97 structure): C[M,N] = A[M,K] @ Bt[N,K]^T + bias[N].
// 128x128 tile, BK=32, 256 threads / 4 waves, 4x4 16x16x32 frags per wave.
// ---------------------------------------------------------------------------
template <bool OUT_BF16>
__global__ __launch_bounds__(256) void gemm_bt(
    const __bf16* __restrict__ A, const __bf16* __restrict__ Bt,
    const float* __restrict__ bias, void* __restrict__ Cout,
    int M, int N, int K)
{
    __shared__ __align__(16) __bf16 Af[8][64][8];
    __shared__ __align__(16) __bf16 Bf[8][64][8];
    const int tid = threadIdx.x;
    const int lane = tid & 63, w = tid >> 6;
    const int lm = lane & 15, lq = lane >> 4;
    const int wm = w >> 1, wn = w & 1;
    const int m0 = blockIdx.y * 128, n0 = blockIdx.x * 128;

    const __bf16* a0 = A + (size_t)(m0 + w * 32 + lm) * K + lq * 8;
    const __bf16* a1 = a0 + (size_t)16 * K;
    const __bf16* b0 = Bt + (size_t)(n0 + w * 32 + lm) * K + lq * 8;
    const __bf16* b1 = b0 + (size_t)16 * K;

    f32x4 acc[4][4];
#pragma unroll
    for (int i = 0; i < 4; ++i)
#pragma unroll
        for (int j = 0; j < 4; ++j) acc[i][j] = (f32x4){0.f, 0.f, 0.f, 0.f};

    for (int k0 = 0; k0 < K; k0 += 32) {
        __syncthreads();
        __builtin_amdgcn_global_load_lds((gptr_t)(const void*)(a0 + k0),
                                         (lptr_t)(void*)&Af[w * 2 + 0][0][0], 16, 0, 0);
        __builtin_amdgcn_global_load_lds((gptr_t)(const void*)(a1 + k0),
                                         (lptr_t)(void*)&Af[w * 2 + 1][0][0], 16, 0, 0);
        __builtin_amdgcn_global_load_lds((gptr_t)(const void*)(b0 + k0),
                                         (lptr_t)(void*)&Bf[w * 2 + 0][0][0], 16, 0, 0);
        __builtin_amdgcn_global_load_lds((gptr_t)(const void*)(b1 + k0),
                                         (lptr_t)(void*)&Bf[w * 2 + 1][0][0], 16, 0, 0);
        __syncthreads();

        bf16x8 av[4], bv[4];
#pragma unroll
        for (int i = 0; i < 4; ++i) {
            av[i] = *(const bf16x8*)&Af[wm * 4 + i][lane][0];
            bv[i] = *(const bf16x8*)&Bf[wn * 4 + i][lane][0];
        }
#pragma unroll
        for (int i = 0; i < 4; ++i)
#pragma unroll
            for (int j = 0; j < 4; ++j)
                acc[i][j] = __builtin_amdgcn_mfma_f32_16x16x32_bf16(
                    av[i], bv[j], acc[i][j], 0, 0, 0);
    }

#pragma unroll
    for (int i = 0; i < 4; ++i) {
        int rowb = m0 + wm * 64 + i * 16 + lq * 4;
#pragma unroll
        for (int j = 0; j < 4; ++j) {
            int col = n0 + wn * 64 + j * 16 + lm;
            float bcol = bias[col];
#pragma unroll
            for (int r = 0; r < 4; ++r) {
                float v = acc[i][j][r] + bcol;
                if (OUT_BF16)
                    ((__bf16*)Cout)[(size_t)(rowb + r) * N + col] = (__bf16)v;
                else
                    ((float*)Cout)[(size_t)(rowb + r) * N + col] = v;
            }
        }
    }
}

// ---------------------------------------------------------------------------
// RoPE on bf16 qkv: q rope'd * (0.125*log2e) in place (exp2-domain softmax);
// k rope'd -> Kb[bh][t][64]; v -> Vt[bh][64][t] (LDS transpose).
// ---------------------------------------------------------------------------
__global__ __launch_bounds__(256) void ropecvt(
    __bf16* qkv, __bf16* __restrict__ Kb, __bf16* __restrict__ Vt)
{
    __shared__ __bf16 vt[64][72];
    const int tid = threadIdx.x;
    const int t0 = blockIdx.x * 64;
    const int bh = blockIdx.y;
    const int b = bh >> 4, h = bh & 15;
    __bf16* base = qkv + ((size_t)(b * T_DIM + t0)) * C3_DIM + h * D_DIM;

    {
        int rr = tid >> 3, cc = (tid & 7) * 8;
#pragma unroll
        for (int it = 0; it < 2; ++it) {
            int r = it * 32 + rr;
            *(bf16x8*)&vt[r][cc] =
                *(const bf16x8*)&base[(size_t)r * C3_DIM + 2 * C_DIM + cc];
        }
    }

    const float QSCALE = 0.125f * 1.44269504089f;  // 1/sqrt(D) * log2(e)

#pragma unroll
    for (int p = 0; p < 8; ++p) {
        int idx = tid + p * 256;          // 64 t x 32 pairs
        int tl = idx >> 5, i = idx & 31;
        float theta = powf(10000.0f, -(float)i / 32.0f);
        float ang = (float)(t0 + tl) * theta;
        float s, c;
        sincosf(ang, &s, &c);
        __bf16* qp = &base[(size_t)tl * C3_DIM + 2 * i];
        float qx = (float)qp[0], qy = (float)qp[1];
        bf16x2 qo = { (__bf16)((qx * c - qy * s) * QSCALE),
                      (__bf16)((qx * s + qy * c) * QSCALE) };
        *(bf16x2*)qp = qo;
        float kx = (float)qp[C_DIM], ky = (float)qp[C_DIM + 1];
        bf16x2 ko = { (__bf16)(kx * c - ky * s), (__bf16)(kx * s + ky * c) };
        *(bf16x2*)(Kb + ((size_t)bh * T_DIM + t0 + tl) * D_DIM + 2 * i) = ko;
    }

    __syncthreads();

    int dd = tid >> 2, tc0 = (tid & 3) * 16;
    __align__(16) __bf16 tmp[16];
#pragma unroll
    for (int j = 0; j < 16; ++j) tmp[j] = vt[tc0 + j][dd];
    __bf16* vo = Vt + ((size_t)bh * D_DIM + dd) * T_DIM + t0 + tc0;
    *(bf16x8*)vo = *(bf16x8*)&tmp[0];
    *(bf16x8*)(vo + 8) = *(bf16x8*)&tmp[8];
}

// ---------------------------------------------------------------------------
// MFMA flash attention v3: transposed-S dataflow.
// S^T = K @ Q^T (A/B frag layouts coincide -> same staging, swapped operands).
// Lane owns ONE softmax row (q = lane&15): local tree + 2 shfls (vs 32).
// P[q][t] write is 4x ds_write_b64 (vs 16x b16); b128 reads unchanged.
// O^T accumulated; epilogue transposes via 4x 8B stores per d-block.
// ---------------------------------------------------------------------------
__global__ __launch_bounds__(256) void attn_mfma(
    const __bf16* __restrict__ qkvb, const __bf16* __restrict__ Kb,
    const __bf16* __restrict__ Vt, __bf16* __restrict__ yb)
{
    __shared__ __align__(16) __bf16 Kf[8][64][8];   // 8 KB
    __shared__ __align__(16) __bf16 Vf[8][64][8];   // 8 KB
    __shared__ __align__(16) __bf16 Pb[4][16][72];  // 9.2 KB  [w][q][t]

    const int tid = threadIdx.x;
    const int bh = blockIdx.x;                  // 0..63
    const int qt = 31 - blockIdx.y;             // heavy first
    const int b = bh >> 4, h = bh & 15;
    const int lane = tid & 63, w = tid >> 6;
    const int m = lane & 15, qq = lane >> 4;

    // ---- Q B-fragments: direct global loads (pre-rope'd, pre-scaled).
    // B-frag: col q = m, k d = qq*8+j  -> same bytes as the old A-frag.
    const __bf16* qrow = qkvb +
        ((size_t)(b * T_DIM + qt * 64 + w * 16 + m)) * C3_DIM + h * D_DIM + qq * 8;
    bf16x8 qreg[2];
    qreg[0] = *(const bf16x8*)qrow;
    qreg[1] = *(const bf16x8*)(qrow + 32);

    float m_i = -1e30f, l_i = 0.f;
    f32x4 acc[4];   // O^T: acc[db][r] = O[q=m][d=db*16+qq*4+r]
#pragma unroll
    for (int db = 0; db < 4; ++db) acc[db] = (f32x4){0.f, 0.f, 0.f, 0.f};

    const __bf16* kgbase = Kb + (size_t)bh * T_DIM * D_DIM;
    const __bf16* vgbase = Vt + (size_t)bh * D_DIM * T_DIM;

    for (int kt = 0; kt <= qt; ++kt) {
        __syncthreads();   // all waves done reading Kf/Vf of prev iter
#pragma unroll
        for (int c = 0; c < 2; ++c) {
            const __bf16* kg = kgbase +
                ((size_t)(kt * 64 + w * 16 + m)) * D_DIM + c * 32 + qq * 8;
            __builtin_amdgcn_global_load_lds(
                (gptr_t)(const void*)kg,
                (lptr_t)(void*)&Kf[w * 2 + c][0][0], 16, 0, 0);
            const __bf16* vg = vgbase +
                ((size_t)(w * 16 + m)) * T_DIM + kt * 64 + c * 32 + qq * 8;
            __builtin_amdgcn_global_load_lds(
                (gptr_t)(const void*)vg,
                (lptr_t)(void*)&Vf[w * 2 + c][0][0], 16, 0, 0);
        }
        __syncthreads();   // staging visible

        // ---- S^T = K @ Q^T : sv[nb][r] = S[q=m][t=nb*16+qq*4+r]
        f32x4 sv[4];
#pragma unroll
        for (int nb = 0; nb < 4; ++nb) {
            f32x4 s = (f32x4){0.f, 0.f, 0.f, 0.f};
            s = __builtin_amdgcn_mfma_f32_16x16x32_bf16(
                *(const bf16x8*)&Kf[nb * 2 + 0][lane][0], qreg[0], s, 0, 0, 0);
            s = __builtin_amdgcn_mfma_f32_16x16x32_bf16(
                *(const bf16x8*)&Kf[nb * 2 + 1][lane][0], qreg[1], s, 0, 0, 0);
            sv[nb] = s;
        }

        // ---- causal mask (diagonal tile): mask t_local > q_local
        if (kt == qt) {
            int qlocal = w * 16 + m;
#pragma unroll
            for (int nb = 0; nb < 4; ++nb) {
                int tb = nb * 16 + qq * 4;
#pragma unroll
                for (int r = 0; r < 4; ++r)
                    if (tb + r > qlocal) sv[nb][r] = -1e30f;
            }
        }

        // ---- online softmax: whole row in-lane; cross only over qq (2 shfl)
        float mt0 = fmaxf(fmaxf(sv[0][0], sv[0][1]), fmaxf(sv[0][2], sv[0][3]));
        float mt1 = fmaxf(fmaxf(sv[1][0], sv[1][1]), fmaxf(sv[1][2], sv[1][3]));
        float mt2 = fmaxf(fmaxf(sv[2][0], sv[2][1]), fmaxf(sv[2][2], sv[2][3]));
        float mt3 = fmaxf(fmaxf(sv[3][0], sv[3][1]), fmaxf(sv[3][2], sv[3][3]));
        float mt = fmaxf(fmaxf(mt0, mt1), fmaxf(mt2, mt3));
        mt = fmaxf(mt, __shfl_xor(mt, 16));
        mt = fmaxf(mt, __shfl_xor(mt, 32));
        float mnew = fmaxf(m_i, mt);
        float alpha = exp2f(m_i - mnew);
        float ll = 0.f;
#pragma unroll
        for (int nb = 0; nb < 4; ++nb) {
            float p0 = exp2f(sv[nb][0] - mnew);
            float p1 = exp2f(sv[nb][1] - mnew);
            float p2 = exp2f(sv[nb][2] - mnew);
            float p3 = exp2f(sv[nb][3] - mnew);
            sv[nb][0] = p0; sv[nb][1] = p1; sv[nb][2] = p2; sv[nb][3] = p3;
            ll += (p0 + p1) + (p2 + p3);
        }
        ll += __shfl_xor(ll, 16);
        ll += __shfl_xor(ll, 32);
        l_i = l_i * alpha + ll;
        m_i = mnew;
#pragma unroll
        for (int db = 0; db < 4; ++db) {
            acc[db][0] *= alpha; acc[db][1] *= alpha;
            acc[db][2] *= alpha; acc[db][3] *= alpha;
        }

        // ---- P[q][t] write: contiguous in t -> 4x b64
#pragma unroll
        for (int nb = 0; nb < 4; ++nb) {
            bf16x4 pv = { (__bf16)sv[nb][0], (__bf16)sv[nb][1],
                          (__bf16)sv[nb][2], (__bf16)sv[nb][3] };
            *(bf16x4*)&Pb[w][m][nb * 16 + qq * 4] = pv;
        }

        // ---- P^T B-fragments (b128, same-wave round trip)
        bf16x8 pf0 = *(const bf16x8*)&Pb[w][m][0 * 32 + qq * 8];
        bf16x8 pf1 = *(const bf16x8*)&Pb[w][m][1 * 32 + qq * 8];

        // ---- O^T += V^T @ P^T
#pragma unroll
        for (int db = 0; db < 4; ++db) {
            acc[db] = __builtin_amdgcn_mfma_f32_16x16x32_bf16(
                *(const bf16x8*)&Vf[db * 2 + 0][lane][0], pf0, acc[db], 0, 0, 0);
            acc[db] = __builtin_amdgcn_mfma_f32_16x16x32_bf16(
                *(const bf16x8*)&Vf[db * 2 + 1][lane][0], pf1, acc[db], 0, 0, 0);
        }
    }

    // ---- epilogue: O[q=m][d] = acc^T; 4x 8B stores
    float inv = 1.0f / l_i;
    __bf16* yrow = yb + (size_t)(b * T_DIM + qt * 64 + w * 16 + m) * C_DIM +
                   h * D_DIM + qq * 4;
#pragma unroll
    for (int db = 0; db < 4; ++db) {
        bf16x4 o = { (__bf16)(acc[db][0] * inv), (__bf16)(acc[db][1] * inv),
                     (__bf16)(acc[db][2] * inv), (__bf16)(acc[db][3] * inv) };
        *(bf16x4*)(yrow + db * 16) = o;
    }
}

// ---------------------------------------------------------------------------
extern "C" void kernel_launch(void* const* d_in, const int* in_sizes, int n_in,
                              void* d_out, int out_size, void* d_ws, size_t ws_size,
                              hipStream_t stream)
{
    const float* x     = (const float*)d_in[0];
    const float* Wqkv  = (const float*)d_in[1];
    const float* bqkv  = (const float*)d_in[2];
    const float* Wproj = (const float*)d_in[3];
    const float* bproj = (const float*)d_in[4];
    float* out = (float*)d_out;

    char* ws = (char*)d_ws;
    __bf16* qkvb = (__bf16*)(ws);                        // [8192][3072] 48 MB
    __bf16* xb   = (__bf16*)(ws + 50331648ull);          // [8192][1024] 16 MB
    __bf16* yb   = (__bf16*)(ws + 67108864ull);          // [8192][1024] 16 MB
    __bf16* Kb   = (__bf16*)(ws + 83886080ull);          // [64][2048][64] 16 MB
    __bf16* Vt   = (__bf16*)(ws + 100663296ull);         // [64][64][2048] 16 MB
    __bf16* Wqt  = (__bf16*)(ws + 117440512ull);         // [3072][1024] 6 MB
    __bf16* Wpt  = (__bf16*)(ws + 123731968ull);         // [1024][1024] 2 MB

    dim3 blk(256);

    cvt_bf16<<<dim3((B_DIM * T_DIM * C_DIM) / 1024), blk, 0, stream>>>(x, xb);
    transpose_cvt<<<dim3(C3_DIM / 64, C_DIM / 64), blk, 0, stream>>>(
        Wqkv, Wqt, C_DIM, C3_DIM);
    transpose_cvt<<<dim3(C_DIM / 64, C_DIM / 64), blk, 0, stream>>>(
        Wproj, Wpt, C_DIM, C_DIM);

    gemm_bt<true><<<dim3(C3_DIM / 128, (B_DIM * T_DIM) / 128), blk, 0, stream>>>(
        xb, Wqt, bqkv, qkvb, B_DIM * T_DIM, C3_DIM, C_DIM);

    ropecvt<<<dim3(T_DIM / 64, B_DIM * H_DIM), blk, 0, stream>>>(qkvb, Kb, Vt);

    attn_mfma<<<dim3(B_DIM * H_DIM, T_DIM / 64), blk, 0, stream>>>(
        qkvb, Kb, Vt, yb);

    gemm_bt<false><<<dim3(C_DIM / 128, (B_DIM * T_DIM) / 128), blk, 0, stream>>>(
        yb, Wpt, bproj, out, B_DIM * T_DIM, C_DIM, C_DIM);
}